// Round 12
// baseline (880.471 us; speedup 1.0000x reference)
//
#include <hip/hip_runtime.h>

#define BB 16
#define SS 1024
#define TT 512
#define DD 256
#define HH 8
#define LL 4
#define FFN 1024
#define DHH 32
#define MROWS (BB*SS)   // 16384

typedef short bf16x8 __attribute__((ext_vector_type(8)));
typedef short bf16x4 __attribute__((ext_vector_type(4)));
typedef float f32x4 __attribute__((ext_vector_type(4)));
typedef float f32x2 __attribute__((ext_vector_type(2)));
typedef unsigned int u32x2 __attribute__((ext_vector_type(2)));

__device__ __forceinline__ unsigned short f2bf(float f) {
    unsigned int u = __float_as_uint(f);
    unsigned int r = (u + 0x7fffu + ((u >> 16) & 1u)) >> 16;
    return (unsigned short)r;
}
__device__ __forceinline__ float bf2f(unsigned short h) {
    return __uint_as_float(((unsigned int)h) << 16);
}
// truncation-pack two fp32 into packed bf16x2
__device__ __forceinline__ unsigned int packbf(float a, float b) {
    return (__float_as_uint(a) >> 16) | (__float_as_uint(b) & 0xffff0000u);
}
// one v_perm_b32: low16 = bf16(p0), high16 = bf16(p1)
__device__ __forceinline__ unsigned int packbf_perm(float p0, float p1) {
    return __builtin_amdgcn_perm(__float_as_uint(p1), __float_as_uint(p0), 0x07060302u);
}

// 16x16x16 bf16 MFMA with intrinsic-name portability guard
__device__ __forceinline__ f32x4 mfma16_bf16(bf16x4 a, bf16x4 b, f32x4 c) {
#if __has_builtin(__builtin_amdgcn_mfma_f32_16x16x16_bf16)
    return __builtin_amdgcn_mfma_f32_16x16x16_bf16(a, b, c, 0, 0, 0);
#elif __has_builtin(__builtin_amdgcn_mfma_f32_16x16x16bf16_1k)
    return __builtin_amdgcn_mfma_f32_16x16x16bf16_1k(a, b, c, 0, 0, 0);
#else
    f32x4 d;
    asm("v_mfma_f32_16x16x16_bf16 %0, %1, %2, %3" : "=v"(d) : "v"(a), "v"(b), "v"(c));
    return d;
#endif
}

// async global->LDS, 16B per lane. LDS dest must be wave-uniform base + lane*16.
__device__ __forceinline__ void g2l16(const unsigned short* g, unsigned short* l) {
    __builtin_amdgcn_global_load_lds(
        (const __attribute__((address_space(1))) unsigned int*)g,
        (__attribute__((address_space(3))) unsigned int*)l, 16, 0, 0);
}

// ---------------- weight conversion (fp32 -> bf16) ----------------
__global__ __launch_bounds__(256) void convert_weights(
    const float* __restrict__ w0, const float* __restrict__ w1, const float* __restrict__ w2,
    const float* __restrict__ w3, const float* __restrict__ w4, unsigned short* __restrict__ dst)
{
    int i = blockIdx.x * 256 + threadIdx.x;
    if (i >= 3276800) return;
    float v;
    if (i < 131072)        v = w0[i];
    else if (i < 917504)   v = w1[i - 131072];
    else if (i < 1179648)  v = w2[i - 917504];
    else if (i < 2228224)  v = w3[i - 1179648];
    else                   v = w4[i - 2228224];
    dst[i] = f2bf(v);
}

__global__ __launch_bounds__(256) void convert_x(const float4* __restrict__ x, ushort4* __restrict__ xb, int n4)
{
    int i = blockIdx.x * 256 + threadIdx.x;
    if (i >= n4) return;
    float4 v = x[i];
    ushort4 o;
    o.x = f2bf(v.x); o.y = f2bf(v.y); o.z = f2bf(v.z); o.w = f2bf(v.w);
    xb[i] = o;
}

// ---------------- wide GEMM (qkv / lin1): 128 x BN block, BK=32, permuted-B wide epilogue ----------------
template<int BN, int RELU>
__global__ __launch_bounds__(256, 2) void gemm_lds(
    const unsigned short* __restrict__ A, const unsigned short* __restrict__ Bw,
    const float* __restrict__ bias, void* out, int M, int N, int K)
{
    constexpr int NJ = BN / 32;
    __shared__ __align__(16) unsigned short sA[2][128 * 32];
    __shared__ __align__(16) unsigned short sB[2][BN * 32];
    const int t = threadIdx.x;
    const int lane = t & 63, quad = lane >> 4, l16 = lane & 15;
    const int wave = t >> 6, wm = wave >> 1, wn = wave & 1;
    const int row0 = blockIdx.y * 128, col0 = blockIdx.x * BN;

    const unsigned short* gA = A + (size_t)(row0 + (t >> 2)) * K + (t & 3) * 8;
    const size_t rstep = (size_t)64 * K;
    const unsigned short* gBp[BN / 64];
    #pragma unroll
    for (int p = 0; p < BN / 64; ++p) {
        int l = p * 64 + (t >> 2);
        int wrow = (l & (16 * NJ)) + (l & 15) * NJ + ((l >> 4) & (NJ - 1));
        gBp[p] = Bw + (size_t)(col0 + wrow) * K + (t & 3) * 8;
    }

    f32x4 acc[4][NJ];
    #pragma unroll
    for (int i = 0; i < 4; ++i)
        #pragma unroll
        for (int j = 0; j < NJ; ++j)
            acc[i][j] = (f32x4){0.f, 0.f, 0.f, 0.f};

    g2l16(gA, &sA[0][t * 8]);
    g2l16(gA + rstep, &sA[0][(t + 256) * 8]);
    #pragma unroll
    for (int p = 0; p < BN / 64; ++p)
        g2l16(gBp[p], &sB[0][p * 2048 + t * 8]);

    for (int k0 = 0; k0 < K; k0 += 32) {
        const int cur = (k0 >> 5) & 1;
        __syncthreads();
        if (k0 + 32 < K) {
            const int nxt = cur ^ 1;
            g2l16(gA + k0 + 32, &sA[nxt][t * 8]);
            g2l16(gA + rstep + k0 + 32, &sA[nxt][(t + 256) * 8]);
            #pragma unroll
            for (int p = 0; p < BN / 64; ++p)
                g2l16(gBp[p] + k0 + 32, &sB[nxt][p * 2048 + t * 8]);
        }
        bf16x8 a[4], b[NJ];
        #pragma unroll
        for (int i = 0; i < 4; ++i)
            a[i] = *(const bf16x8*)(&sA[cur][(wm * 64 + i * 16 + l16) * 32 + quad * 8]);
        #pragma unroll
        for (int j = 0; j < NJ; ++j)
            b[j] = *(const bf16x8*)(&sB[cur][(wn * (BN / 2) + j * 16 + l16) * 32 + quad * 8]);
        #pragma unroll
        for (int i = 0; i < 4; ++i)
            #pragma unroll
            for (int j = 0; j < NJ; ++j)
                acc[i][j] = __builtin_amdgcn_mfma_f32_16x16x32_bf16(a[i], b[j], acc[i][j], 0, 0, 0);
    }

    const int colbase = col0 + wn * (BN / 2) + l16 * NJ;
    float bb[NJ];
    #pragma unroll
    for (int j = 0; j < NJ; ++j) bb[j] = bias[colbase + j];
    #pragma unroll
    for (int i = 0; i < 4; ++i) {
        #pragma unroll
        for (int r = 0; r < 4; ++r) {
            int row = row0 + wm * 64 + i * 16 + quad * 4 + r;
            float v[NJ];
            #pragma unroll
            for (int j = 0; j < NJ; ++j) {
                v[j] = acc[i][j][r] + bb[j];
                if (RELU) v[j] = fmaxf(v[j], 0.f);
            }
            unsigned short* dst = (unsigned short*)out + (size_t)row * N + colbase;
            if constexpr (NJ == 4) {
                uint2 w; w.x = packbf(v[0], v[1]); w.y = packbf(v[2], v[3]);
                *(uint2*)dst = w;
            } else {
                uint4 w; w.x = packbf(v[0], v[1]); w.y = packbf(v[2], v[3]);
                w.z = packbf(v[4], v[5]); w.w = packbf(v[6], v[7]);
                *(uint4*)dst = w;
            }
        }
    }
}

// ---------------- N=64-col GEMM (tokenize / out-proj / lin2): 128 x 64 block, BK=64 ----------------
template<int RESID>
__global__ __launch_bounds__(256, 2) void gemm_n64(
    const unsigned short* __restrict__ A, const unsigned short* __restrict__ Bw,
    const float* __restrict__ bias, const float* resid, float* out, int M, int N, int K)
{
    __shared__ __align__(16) unsigned short sA[2][2 * 128 * 32];   // [buf][kh][row][32]
    __shared__ __align__(16) unsigned short sB[2][2 * 64 * 32];
    const int t = threadIdx.x;
    const int lane = t & 63, quad = lane >> 4, l16 = lane & 15;
    const int wave = t >> 6, wm = wave >> 1, wn = wave & 1;
    const int row0 = blockIdx.y * 128, col0 = blockIdx.x * 64;

    const unsigned short* gA = A + (size_t)(row0 + (t >> 2)) * K + (t & 3) * 8;
    const size_t rstep = (size_t)64 * K;
    const int bl = t >> 2;
    const unsigned short* gB = Bw + (size_t)(col0 + (bl & 32) + (bl & 15) * 2 + ((bl >> 4) & 1)) * K + (t & 3) * 8;

    f32x4 acc[4][2];
    #pragma unroll
    for (int i = 0; i < 4; ++i) {
        acc[i][0] = (f32x4){0.f, 0.f, 0.f, 0.f};
        acc[i][1] = (f32x4){0.f, 0.f, 0.f, 0.f};
    }

    auto stage = [&](int k0, int buf) {
        #pragma unroll
        for (int kh = 0; kh < 2; ++kh) {
            #pragma unroll
            for (int rh = 0; rh < 2; ++rh)
                g2l16(gA + (size_t)rh * rstep + k0 + kh * 32,
                      &sA[buf][kh * 4096 + rh * 2048 + t * 8]);
            g2l16(gB + k0 + kh * 32, &sB[buf][kh * 2048 + t * 8]);
        }
    };

    stage(0, 0);
    for (int k0 = 0; k0 < K; k0 += 64) {
        const int cur = (k0 >> 6) & 1;
        __syncthreads();
        if (k0 + 64 < K) stage(k0 + 64, cur ^ 1);
        #pragma unroll
        for (int kh = 0; kh < 2; ++kh) {
            bf16x8 a[4], b[2];
            #pragma unroll
            for (int i = 0; i < 4; ++i)
                a[i] = *(const bf16x8*)(&sA[cur][kh * 4096 + wm * 2048 + (i * 16 + l16) * 32 + quad * 8]);
            b[0] = *(const bf16x8*)(&sB[cur][kh * 2048 + (wn * 32 + l16) * 32 + quad * 8]);
            b[1] = *(const bf16x8*)(&sB[cur][kh * 2048 + (wn * 32 + 16 + l16) * 32 + quad * 8]);
            #pragma unroll
            for (int i = 0; i < 4; ++i) {
                acc[i][0] = __builtin_amdgcn_mfma_f32_16x16x32_bf16(a[i], b[0], acc[i][0], 0, 0, 0);
                acc[i][1] = __builtin_amdgcn_mfma_f32_16x16x32_bf16(a[i], b[1], acc[i][1], 0, 0, 0);
            }
        }
    }

    const int colbase = col0 + wn * 32 + l16 * 2;
    float b0 = bias[colbase], b1 = bias[colbase + 1];
    #pragma unroll
    for (int i = 0; i < 4; ++i) {
        #pragma unroll
        for (int r = 0; r < 4; ++r) {
            int row = row0 + wm * 64 + i * 16 + quad * 4 + r;
            float2 o;
            o.x = acc[i][0][r] + b0;
            o.y = acc[i][1][r] + b1;
            if (RESID) {
                float2 rv = *(const float2*)(resid + (size_t)row * N + colbase);
                o.x += rv.x; o.y += rv.y;
            }
            *(float2*)(out + (size_t)row * N + colbase) = o;
        }
    }
}

// ---------------- LayerNorm over D=256, one wave per row, 4 rows/block, float4 loads ----------------
template<int OUT_BF16>
__global__ __launch_bounds__(256) void ln_rows(const float* __restrict__ in,
    const float* __restrict__ g, const float* __restrict__ bt, void* __restrict__ out)
{
    int wave = threadIdx.x >> 6, lane = threadIdx.x & 63;
    size_t row = (size_t)blockIdx.x * 4 + wave;
    float4 v = ((const float4*)(in + row * DD))[lane];
    float s = v.x + v.y + v.z + v.w;
    #pragma unroll
    for (int m = 32; m >= 1; m >>= 1) s += __shfl_xor(s, m);
    float mean = s * (1.f / DD);
    float dx = v.x - mean, dy = v.y - mean, dz = v.z - mean, dw = v.w - mean;
    float ss = dx * dx + dy * dy + dz * dz + dw * dw;
    #pragma unroll
    for (int m = 32; m >= 1; m >>= 1) ss += __shfl_xor(ss, m);
    float inv = rsqrtf(ss * (1.f / DD) + 1e-5f);
    float4 gv = ((const float4*)g)[lane];
    float4 bv = ((const float4*)bt)[lane];
    float ox = dx * inv * gv.x + bv.x, oy = dy * inv * gv.y + bv.y;
    float oz = dz * inv * gv.z + bv.z, ow = dw * inv * gv.w + bv.w;
    if (OUT_BF16) {
        ushort4 o; o.x = f2bf(ox); o.y = f2bf(oy); o.z = f2bf(oz); o.w = f2bf(ow);
        ((ushort4*)((unsigned short*)out + row * DD))[lane] = o;
    } else {
        ((float4*)((float*)out + row * DD))[lane] = (float4){ox, oy, oz, ow};
    }
}

// ---------------- RoPE + layout (kr natural order now; q pre-scaled by log2e/sqrt(DH)) ----------------
__global__ __launch_bounds__(256) void rope_kernel(const unsigned short* __restrict__ qkv,
    unsigned short* __restrict__ qr, unsigned short* __restrict__ kr, unsigned short* __restrict__ vt)
{
    __shared__ float sc[2][16];
    int row = blockIdx.x;          // b*S + s
    int t = threadIdx.x;           // h*32 + d
    int h = t >> 5, d = t & 31, j = d & 15;
    int b = row >> 10, s = row & 1023;
    if (t < 16) {
        float inv_freq = __expf(-(float)t * 0.575646273248511f);  // 10000^(-t/16)
        float fr = (float)s * inv_freq;
        float c, sn;
        __sincosf(fr, &sn, &c);
        sc[0][t] = c;
        sc[1][t] = sn;
    }
    const unsigned short* rp = qkv + (size_t)row * 768;
    float qv = bf2f(rp[t]);
    float kv = bf2f(rp[256 + t]);
    float vv = bf2f(rp[512 + t]);
    __syncthreads();
    float c = sc[0][j], sn = sc[1][j];
    float qp = __shfl_xor(qv, 16);
    float kp = __shfl_xor(kv, 16);
    const float qscale = 1.4426950408889634f / 5.656854249492381f;  // log2e/sqrt(32)
    float rq = (qv * c + ((d < 16) ? -qp : qp) * sn) * qscale;
    float rk = kv * c + ((d < 16) ? -kp : kp) * sn;
    int bh = (b << 3) | h;
    size_t qi = ((size_t)bh * SS + s) * DHH + d;
    qr[qi] = f2bf(rq);
    kr[qi] = f2bf(rk);
    vt[((size_t)bh * DHH + d) * SS + s] = f2bf(vv);
}

// ---------------- fused attention: LDS-FREE transposed MFMA chain ----------------
// One wave per block, 2x16-query tiles, 64 keys/iter.
// S^T = mfma_16x16x32(A=K-frag, B=Q-frag): C-layout col=q(l16), row=key(quad*4+r).
// exp'd scores, packed in-register, ARE the B-operand of a 16x16x16 MFMA
// (B[n=q(l16)][k=key quad*4+j]) -> O^T = mfma_16x16x16(A=V^T-frag, B=P^T).
// No LDS, no barriers, no lgkmcnt in the loop.
__global__ __launch_bounds__(64) void attn_kernel(
    const unsigned short* __restrict__ qr, const unsigned short* __restrict__ kr,
    const unsigned short* __restrict__ vt, unsigned short* __restrict__ ob)
{
    int lane = threadIdx.x;
    int quad = lane >> 4, l16 = lane & 15;
    int bh = blockIdx.x;
    int q0 = blockIdx.y * 32;
    int b = bh >> 3, h = bh & 7;
    const unsigned short* qbase = qr + ((size_t)bh * SS + q0) * DHH;
    const unsigned short* kbase = kr + (size_t)bh * SS * DHH;
    const unsigned short* vbase = vt + (size_t)bh * DHH * SS;
    bf16x8 qa[2];                               // B-operand of QK: B[n=q][k=dim]
    qa[0] = *(const bf16x8*)(qbase + (size_t)l16 * DHH + quad * 8);
    qa[1] = *(const bf16x8*)(qbase + (size_t)(16 + l16) * DHH + quad * 8);
    f32x4 o[2][2] = {};                         // O^T accumulators [qt][d-half]
    f32x2 ls[2] = {};                           // per-lane partial row sums [qt]
    for (int k0 = 0; k0 < SS; k0 += 64) {
        // K fragments: A[m=key(l16)][k=dim(quad*8..)], 4 chunks of 16 keys (shared by both qt)
        bf16x8 kb[4];
        #pragma unroll
        for (int c = 0; c < 4; ++c)
            kb[c] = *(const bf16x8*)(kbase + (size_t)(k0 + c * 16 + l16) * DHH + quad * 8);
        // V^T fragments: A[m=d(l16)][k=key(quad*4..)], per chunk x d-half, 8B loads
        bf16x4 vA[4][2];
        #pragma unroll
        for (int c = 0; c < 4; ++c)
            #pragma unroll
            for (int dh = 0; dh < 2; ++dh)
                vA[c][dh] = *(const bf16x4*)(vbase + (size_t)(dh * 16 + l16) * SS + k0 + c * 16 + quad * 4);
        #pragma unroll
        for (int qt = 0; qt < 2; ++qt)
            #pragma unroll
            for (int c = 0; c < 4; ++c) {
                f32x4 z = {0.f, 0.f, 0.f, 0.f};
                f32x4 sT = __builtin_amdgcn_mfma_f32_16x16x32_bf16(kb[c], qa[qt], z, 0, 0, 0);
                float p0 = __builtin_amdgcn_exp2f(sT[0]);
                float p1 = __builtin_amdgcn_exp2f(sT[1]);
                float p2 = __builtin_amdgcn_exp2f(sT[2]);
                float p3 = __builtin_amdgcn_exp2f(sT[3]);
                ls[qt] += (f32x2){p0, p1};
                ls[qt] += (f32x2){p2, p3};
                u32x2 uu = {packbf_perm(p0, p1), packbf_perm(p2, p3)};
                bf16x4 pb = __builtin_bit_cast(bf16x4, uu);   // B[n=q][k=quad*4+j]
                o[qt][0] = mfma16_bf16(vA[c][0], pb, o[qt][0]);
                o[qt][1] = mfma16_bf16(vA[c][1], pb, o[qt][1]);
            }
    }
    #pragma unroll
    for (int qt = 0; qt < 2; ++qt) {
        float s = ls[qt][0] + ls[qt][1];
        s += __shfl_xor(s, 16);                 // reduce across quads (q fixed = l16)
        s += __shfl_xor(s, 32);
        float inv = 1.f / s;
        int qrow = q0 + qt * 16 + l16;
        unsigned short* dst = ob + ((size_t)b * SS + qrow) * DD + h * DHH;
        #pragma unroll
        for (int dh = 0; dh < 2; ++dh) {
            uint2 w;
            w.x = packbf_perm(o[qt][dh][0] * inv, o[qt][dh][1] * inv);
            w.y = packbf_perm(o[qt][dh][2] * inv, o[qt][dh][3] * inv);
            *(uint2*)(dst + dh * 16 + quad * 4) = w;   // dims dh*16 + quad*4 .. +3
        }
    }
}

extern "C" void kernel_launch(void* const* d_in, const int* in_sizes, int n_in,
                              void* d_out, int out_size, void* d_ws, size_t ws_size,
                              hipStream_t stream)
{
    const float* x        = (const float*)d_in[0];
    const float* tok_w    = (const float*)d_in[1];
    const float* tok_b    = (const float*)d_in[2];
    const float* tnorm_g  = (const float*)d_in[3];
    const float* tnorm_b  = (const float*)d_in[4];
    const float* in_proj_w= (const float*)d_in[5];
    const float* in_proj_b= (const float*)d_in[6];
    const float* out_w    = (const float*)d_in[7];
    const float* out_b    = (const float*)d_in[8];
    const float* ln1_g    = (const float*)d_in[9];
    const float* ln1_b    = (const float*)d_in[10];
    const float* ln2_g    = (const float*)d_in[11];
    const float* ln2_b    = (const float*)d_in[12];
    const float* lin1_w   = (const float*)d_in[13];
    const float* lin1_b   = (const float*)d_in[14];
    const float* lin2_w   = (const float*)d_in[15];
    const float* lin2_b   = (const float*)d_in[16];
    const float* fnorm_g  = (const float*)d_in[17];
    const float* fnorm_b  = (const float*)d_in[18];

    char* ws = (char*)d_ws;
    unsigned short* wb        = (unsigned short*)ws;
    unsigned short* wb_tok    = wb;
    unsigned short* wb_inproj = wb + 131072;
    unsigned short* wb_out    = wb + 917504;
    unsigned short* wb_lin1   = wb + 1179648;
    unsigned short* wb_lin2   = wb + 2228224;
    unsigned short* qkvb = (unsigned short*)(ws + 6553600);
    unsigned short* xb   = qkvb;                                     // tokenize-only alias
    float*          h    = (float*)(ws + 31719424);
    unsigned short* y    = (unsigned short*)(ws + 48496640);
    unsigned short* qr   = (unsigned short*)(ws + 56885248);
    unsigned short* kr   = (unsigned short*)(ws + 65273856);
    unsigned short* vt   = (unsigned short*)(ws + 73662464);
    unsigned short* ob   = (unsigned short*)(ws + 82051072);
    unsigned short* a1   = (unsigned short*)(ws + 90439680);
    float*          t0   = (float*)(ws + 90439680);                  // aliases a1 (pre-layer only)

    convert_weights<<<dim3(12800), dim3(256), 0, stream>>>(tok_w, in_proj_w, out_w, lin1_w, lin2_w, wb);
    convert_x<<<dim3(8192), dim3(256), 0, stream>>>((const float4*)x, (ushort4*)xb, MROWS * TT / 4);

    // tokenize: t0 = x @ tok_w^T + tok_b ; h = LN(t0)
    gemm_n64<0><<<dim3(DD/64, MROWS/128), dim3(256), 0, stream>>>(
        xb, wb_tok, tok_b, nullptr, t0, MROWS, DD, TT);
    ln_rows<0><<<dim3(MROWS/4), dim3(256), 0, stream>>>(t0, tnorm_g, tnorm_b, h);

    for (int i = 0; i < LL; ++i) {
        ln_rows<1><<<dim3(MROWS/4), dim3(256), 0, stream>>>(h, ln1_g + i*DD, ln1_b + i*DD, y);
        gemm_lds<128,0><<<dim3((3*DD)/128, MROWS/128), dim3(256), 0, stream>>>(
            y, wb_inproj + (size_t)i*3*DD*DD, in_proj_b + i*3*DD, qkvb, MROWS, 3*DD, DD);
        rope_kernel<<<dim3(MROWS), dim3(256), 0, stream>>>(qkvb, qr, kr, vt);
        attn_kernel<<<dim3(BB*HH, SS/32), dim3(64), 0, stream>>>(qr, kr, vt, ob);
        gemm_n64<1><<<dim3(DD/64, MROWS/128), dim3(256), 0, stream>>>(
            ob, wb_out + (size_t)i*DD*DD, out_b + i*DD, h, h, MROWS, DD, DD);
        ln_rows<1><<<dim3(MROWS/4), dim3(256), 0, stream>>>(h, ln2_g + i*DD, ln2_b + i*DD, y);
        gemm_lds<256,1><<<dim3(FFN/256, MROWS/128), dim3(256), 0, stream>>>(
            y, wb_lin1 + (size_t)i*FFN*DD, lin1_b + i*FFN, a1, MROWS, FFN, DD);
        gemm_n64<1><<<dim3(DD/64, MROWS/128), dim3(256), 0, stream>>>(
            a1, wb_lin2 + (size_t)i*DD*FFN, lin2_b + i*DD, h, h, MROWS, DD, FFN);
    }
    ln_rows<0><<<dim3(MROWS/4), dim3(256), 0, stream>>>(h, fnorm_g, fnorm_b, (float*)d_out);
}

// Round 14
// 818.258 us; speedup vs baseline: 1.0760x; 1.0760x over previous
//
#include <hip/hip_runtime.h>

#define BB 16
#define SS 1024
#define TT 512
#define DD 256
#define HH 8
#define LL 4
#define FFN 1024
#define DHH 32
#define MROWS (BB*SS)   // 16384

typedef short bf16x8 __attribute__((ext_vector_type(8)));
typedef float f32x4 __attribute__((ext_vector_type(4)));
typedef float f32x2 __attribute__((ext_vector_type(2)));

__device__ __forceinline__ unsigned short f2bf(float f) {
    unsigned int u = __float_as_uint(f);
    unsigned int r = (u + 0x7fffu + ((u >> 16) & 1u)) >> 16;
    return (unsigned short)r;
}
__device__ __forceinline__ float bf2f(unsigned short h) {
    return __uint_as_float(((unsigned int)h) << 16);
}
__device__ __forceinline__ unsigned int packbf(float a, float b) {
    return (__float_as_uint(a) >> 16) | (__float_as_uint(b) & 0xffff0000u);
}
// one v_perm_b32: low16 = bf16trunc(p0), high16 = bf16trunc(p1)
__device__ __forceinline__ unsigned int packbf_perm(float p0, float p1) {
    return __builtin_amdgcn_perm(__float_as_uint(p1), __float_as_uint(p0), 0x07060302u);
}

// async global->LDS, 16B per lane. LDS dest must be wave-uniform base + lane*16.
__device__ __forceinline__ void g2l16(const unsigned short* g, unsigned short* l) {
    __builtin_amdgcn_global_load_lds(
        (const __attribute__((address_space(1))) unsigned int*)g,
        (__attribute__((address_space(3))) unsigned int*)l, 16, 0, 0);
}

// ---------------- weight conversion (fp32 -> bf16) ----------------
__global__ __launch_bounds__(256) void convert_weights(
    const float* __restrict__ w0, const float* __restrict__ w1, const float* __restrict__ w2,
    const float* __restrict__ w3, const float* __restrict__ w4, unsigned short* __restrict__ dst)
{
    int i = blockIdx.x * 256 + threadIdx.x;
    if (i >= 3276800) return;
    float v;
    if (i < 131072)        v = w0[i];
    else if (i < 917504)   v = w1[i - 131072];
    else if (i < 1179648)  v = w2[i - 917504];
    else if (i < 2228224)  v = w3[i - 1179648];
    else                   v = w4[i - 2228224];
    dst[i] = f2bf(v);
}

__global__ __launch_bounds__(256) void convert_x(const float4* __restrict__ x, ushort4* __restrict__ xb, int n4)
{
    int i = blockIdx.x * 256 + threadIdx.x;
    if (i >= n4) return;
    float4 v = x[i];
    ushort4 o;
    o.x = f2bf(v.x); o.y = f2bf(v.y); o.z = f2bf(v.z); o.w = f2bf(v.w);
    xb[i] = o;
}

// ---------------- wide GEMM (qkv / lin1): 128 x BN block, BK=32, permuted-B wide epilogue ----------------
template<int BN, int RELU>
__global__ __launch_bounds__(256, 2) void gemm_lds(
    const unsigned short* __restrict__ A, const unsigned short* __restrict__ Bw,
    const float* __restrict__ bias, void* out, int M, int N, int K)
{
    constexpr int NJ = BN / 32;
    __shared__ __align__(16) unsigned short sA[2][128 * 32];
    __shared__ __align__(16) unsigned short sB[2][BN * 32];
    const int t = threadIdx.x;
    const int lane = t & 63, quad = lane >> 4, l16 = lane & 15;
    const int wave = t >> 6, wm = wave >> 1, wn = wave & 1;
    const int row0 = blockIdx.y * 128, col0 = blockIdx.x * BN;

    const unsigned short* gA = A + (size_t)(row0 + (t >> 2)) * K + (t & 3) * 8;
    const size_t rstep = (size_t)64 * K;
    const unsigned short* gBp[BN / 64];
    #pragma unroll
    for (int p = 0; p < BN / 64; ++p) {
        int l = p * 64 + (t >> 2);
        int wrow = (l & (16 * NJ)) + (l & 15) * NJ + ((l >> 4) & (NJ - 1));
        gBp[p] = Bw + (size_t)(col0 + wrow) * K + (t & 3) * 8;
    }

    f32x4 acc[4][NJ];
    #pragma unroll
    for (int i = 0; i < 4; ++i)
        #pragma unroll
        for (int j = 0; j < NJ; ++j)
            acc[i][j] = (f32x4){0.f, 0.f, 0.f, 0.f};

    g2l16(gA, &sA[0][t * 8]);
    g2l16(gA + rstep, &sA[0][(t + 256) * 8]);
    #pragma unroll
    for (int p = 0; p < BN / 64; ++p)
        g2l16(gBp[p], &sB[0][p * 2048 + t * 8]);

    for (int k0 = 0; k0 < K; k0 += 32) {
        const int cur = (k0 >> 5) & 1;
        __syncthreads();
        if (k0 + 32 < K) {
            const int nxt = cur ^ 1;
            g2l16(gA + k0 + 32, &sA[nxt][t * 8]);
            g2l16(gA + rstep + k0 + 32, &sA[nxt][(t + 256) * 8]);
            #pragma unroll
            for (int p = 0; p < BN / 64; ++p)
                g2l16(gBp[p] + k0 + 32, &sB[nxt][p * 2048 + t * 8]);
        }
        bf16x8 a[4], b[NJ];
        #pragma unroll
        for (int i = 0; i < 4; ++i)
            a[i] = *(const bf16x8*)(&sA[cur][(wm * 64 + i * 16 + l16) * 32 + quad * 8]);
        #pragma unroll
        for (int j = 0; j < NJ; ++j)
            b[j] = *(const bf16x8*)(&sB[cur][(wn * (BN / 2) + j * 16 + l16) * 32 + quad * 8]);
        #pragma unroll
        for (int i = 0; i < 4; ++i)
            #pragma unroll
            for (int j = 0; j < NJ; ++j)
                acc[i][j] = __builtin_amdgcn_mfma_f32_16x16x32_bf16(a[i], b[j], acc[i][j], 0, 0, 0);
    }

    const int colbase = col0 + wn * (BN / 2) + l16 * NJ;
    float bb[NJ];
    #pragma unroll
    for (int j = 0; j < NJ; ++j) bb[j] = bias[colbase + j];
    #pragma unroll
    for (int i = 0; i < 4; ++i) {
        #pragma unroll
        for (int r = 0; r < 4; ++r) {
            int row = row0 + wm * 64 + i * 16 + quad * 4 + r;
            float v[NJ];
            #pragma unroll
            for (int j = 0; j < NJ; ++j) {
                v[j] = acc[i][j][r] + bb[j];
                if (RELU) v[j] = fmaxf(v[j], 0.f);
            }
            unsigned short* dst = (unsigned short*)out + (size_t)row * N + colbase;
            if constexpr (NJ == 4) {
                uint2 w; w.x = packbf(v[0], v[1]); w.y = packbf(v[2], v[3]);
                *(uint2*)dst = w;
            } else {
                uint4 w; w.x = packbf(v[0], v[1]); w.y = packbf(v[2], v[3]);
                w.z = packbf(v[4], v[5]); w.w = packbf(v[6], v[7]);
                *(uint4*)dst = w;
            }
        }
    }
}

// ---------------- N=64-col GEMM (tokenize / out-proj / lin2): 128 x 64 block, BK=64 ----------------
template<int RESID>
__global__ __launch_bounds__(256, 2) void gemm_n64(
    const unsigned short* __restrict__ A, const unsigned short* __restrict__ Bw,
    const float* __restrict__ bias, const float* resid, float* out, int M, int N, int K)
{
    __shared__ __align__(16) unsigned short sA[2][2 * 128 * 32];   // [buf][kh][row][32]
    __shared__ __align__(16) unsigned short sB[2][2 * 64 * 32];
    const int t = threadIdx.x;
    const int lane = t & 63, quad = lane >> 4, l16 = lane & 15;
    const int wave = t >> 6, wm = wave >> 1, wn = wave & 1;
    const int row0 = blockIdx.y * 128, col0 = blockIdx.x * 64;

    const unsigned short* gA = A + (size_t)(row0 + (t >> 2)) * K + (t & 3) * 8;
    const size_t rstep = (size_t)64 * K;
    const int bl = t >> 2;
    const unsigned short* gB = Bw + (size_t)(col0 + (bl & 32) + (bl & 15) * 2 + ((bl >> 4) & 1)) * K + (t & 3) * 8;

    f32x4 acc[4][2];
    #pragma unroll
    for (int i = 0; i < 4; ++i) {
        acc[i][0] = (f32x4){0.f, 0.f, 0.f, 0.f};
        acc[i][1] = (f32x4){0.f, 0.f, 0.f, 0.f};
    }

    auto stage = [&](int k0, int buf) {
        #pragma unroll
        for (int kh = 0; kh < 2; ++kh) {
            #pragma unroll
            for (int rh = 0; rh < 2; ++rh)
                g2l16(gA + (size_t)rh * rstep + k0 + kh * 32,
                      &sA[buf][kh * 4096 + rh * 2048 + t * 8]);
            g2l16(gB + k0 + kh * 32, &sB[buf][kh * 2048 + t * 8]);
        }
    };

    stage(0, 0);
    for (int k0 = 0; k0 < K; k0 += 64) {
        const int cur = (k0 >> 6) & 1;
        __syncthreads();
        if (k0 + 64 < K) stage(k0 + 64, cur ^ 1);
        #pragma unroll
        for (int kh = 0; kh < 2; ++kh) {
            bf16x8 a[4], b[2];
            #pragma unroll
            for (int i = 0; i < 4; ++i)
                a[i] = *(const bf16x8*)(&sA[cur][kh * 4096 + wm * 2048 + (i * 16 + l16) * 32 + quad * 8]);
            b[0] = *(const bf16x8*)(&sB[cur][kh * 2048 + (wn * 32 + l16) * 32 + quad * 8]);
            b[1] = *(const bf16x8*)(&sB[cur][kh * 2048 + (wn * 32 + 16 + l16) * 32 + quad * 8]);
            #pragma unroll
            for (int i = 0; i < 4; ++i) {
                acc[i][0] = __builtin_amdgcn_mfma_f32_16x16x32_bf16(a[i], b[0], acc[i][0], 0, 0, 0);
                acc[i][1] = __builtin_amdgcn_mfma_f32_16x16x32_bf16(a[i], b[1], acc[i][1], 0, 0, 0);
            }
        }
    }

    const int colbase = col0 + wn * 32 + l16 * 2;
    float b0 = bias[colbase], b1 = bias[colbase + 1];
    #pragma unroll
    for (int i = 0; i < 4; ++i) {
        #pragma unroll
        for (int r = 0; r < 4; ++r) {
            int row = row0 + wm * 64 + i * 16 + quad * 4 + r;
            float2 o;
            o.x = acc[i][0][r] + b0;
            o.y = acc[i][1][r] + b1;
            if (RESID) {
                float2 rv = *(const float2*)(resid + (size_t)row * N + colbase);
                o.x += rv.x; o.y += rv.y;
            }
            *(float2*)(out + (size_t)row * N + colbase) = o;
        }
    }
}

// ---------------- LayerNorm over D=256, one wave per row, 4 rows/block, float4 loads ----------------
template<int OUT_BF16>
__global__ __launch_bounds__(256) void ln_rows(const float* __restrict__ in,
    const float* __restrict__ g, const float* __restrict__ bt, void* __restrict__ out)
{
    int wave = threadIdx.x >> 6, lane = threadIdx.x & 63;
    size_t row = (size_t)blockIdx.x * 4 + wave;
    float4 v = ((const float4*)(in + row * DD))[lane];
    float s = v.x + v.y + v.z + v.w;
    #pragma unroll
    for (int m = 32; m >= 1; m >>= 1) s += __shfl_xor(s, m);
    float mean = s * (1.f / DD);
    float dx = v.x - mean, dy = v.y - mean, dz = v.z - mean, dw = v.w - mean;
    float ss = dx * dx + dy * dy + dz * dz + dw * dw;
    #pragma unroll
    for (int m = 32; m >= 1; m >>= 1) ss += __shfl_xor(ss, m);
    float inv = rsqrtf(ss * (1.f / DD) + 1e-5f);
    float4 gv = ((const float4*)g)[lane];
    float4 bv = ((const float4*)bt)[lane];
    float ox = dx * inv * gv.x + bv.x, oy = dy * inv * gv.y + bv.y;
    float oz = dz * inv * gv.z + bv.z, ow = dw * inv * gv.w + bv.w;
    if (OUT_BF16) {
        ushort4 o; o.x = f2bf(ox); o.y = f2bf(oy); o.z = f2bf(oz); o.w = f2bf(ow);
        ((ushort4*)((unsigned short*)out + row * DD))[lane] = o;
    } else {
        ((float4*)((float*)out + row * DD))[lane] = (float4){ox, oy, oz, ow};
    }
}

// ---------------- RoPE + layout (kr even/odd interleaved per 32-chunk) ----------------
__global__ __launch_bounds__(256) void rope_kernel(const unsigned short* __restrict__ qkv,
    unsigned short* __restrict__ qr, unsigned short* __restrict__ kr, unsigned short* __restrict__ vt)
{
    __shared__ float sc[2][16];
    int row = blockIdx.x;          // b*S + s
    int t = threadIdx.x;           // h*32 + d
    int h = t >> 5, d = t & 31, j = d & 15;
    int b = row >> 10, s = row & 1023;
    if (t < 16) {
        float inv_freq = __expf(-(float)t * 0.575646273248511f);  // 10000^(-t/16)
        float fr = (float)s * inv_freq;
        float c, sn;
        __sincosf(fr, &sn, &c);
        sc[0][t] = c;
        sc[1][t] = sn;
    }
    const unsigned short* rp = qkv + (size_t)row * 768;
    float qv = bf2f(rp[t]);
    float kv = bf2f(rp[256 + t]);
    float vv = bf2f(rp[512 + t]);
    __syncthreads();
    float c = sc[0][j], sn = sc[1][j];
    float qp = __shfl_xor(qv, 16);
    float kp = __shfl_xor(kv, 16);
    const float qscale = 1.4426950408889634f / 5.656854249492381f;  // log2e/sqrt(32)
    float rq = (qv * c + ((d < 16) ? -qp : qp) * sn) * qscale;
    float rk = kv * c + ((d < 16) ? -kp : kp) * sn;
    int bh = (b << 3) | h;
    qr[((size_t)bh * SS + s) * DHH + d] = f2bf(rq);
    int jj = s & 31;
    int sp = (s & ~31) | (((jj & 1) << 4) | (jj >> 1));   // even/odd interleave
    kr[((size_t)bh * SS + sp) * DHH + d] = f2bf(rk);
    vt[((size_t)bh * DHH + d) * SS + s] = f2bf(vv);
}

// ---------------- fused attention, KEY-SPLIT x2 (flash-decode; exact for no-max softmax) ----------------
// Round-11 core: 1 wave/block, 2x16-query tiles, 64 keys/iter, 4 indep exp->LDS->PV chains.
// blockIdx.z = key-half. Writes UNNORMALIZED fp32 O-partials + row-sum partials.
// Grid 8192 blocks -> 32 blocks/CU available (was 16).
#define PS 40   // P-tile LDS row stride (u16)
#define POH 4194304   // floats per po half (BB*HH*SS*DHH)
__global__ __launch_bounds__(64) void attn_kernel(
    const unsigned short* __restrict__ qr, const unsigned short* __restrict__ kr,
    const unsigned short* __restrict__ vt, float* __restrict__ po, float* __restrict__ pl)
{
    __shared__ __align__(16) unsigned short plds[4][16 * PS];  // [qt*2+kc], 5 KB
    int lane = threadIdx.x;
    int quad = lane >> 4, l16 = lane & 15;
    int bh = blockIdx.x;
    int q0 = blockIdx.y * 32;
    int half = blockIdx.z;
    int kbeg = half * (SS / 2);
    const unsigned short* qbase = qr + ((size_t)bh * SS + q0) * DHH;
    const unsigned short* kbase = kr + (size_t)bh * SS * DHH;
    const unsigned short* vbase = vt + (size_t)bh * DHH * SS;
    bf16x8 qa[2];
    qa[0] = *(const bf16x8*)(qbase + (size_t)l16 * DHH + quad * 8);
    qa[1] = *(const bf16x8*)(qbase + (size_t)(16 + l16) * DHH + quad * 8);
    f32x4 o[2][2] = {};
    f32x2 lsum2[2][4] = {};
    for (int k0 = kbeg; k0 < kbeg + SS / 2; k0 += 64) {
        bf16x8 kb[2][2], vb[2][2];
        #pragma unroll
        for (int kc = 0; kc < 2; ++kc) {
            const unsigned short* kp = kbase + (size_t)(k0 + kc * 32) * DHH;
            kb[kc][0] = *(const bf16x8*)(kp + (size_t)l16 * DHH + quad * 8);        // even keys
            kb[kc][1] = *(const bf16x8*)(kp + (size_t)(16 + l16) * DHH + quad * 8); // odd keys
            vb[kc][0] = *(const bf16x8*)(vbase + (size_t)l16 * SS + k0 + kc * 32 + quad * 8);
            vb[kc][1] = *(const bf16x8*)(vbase + (size_t)(l16 + 16) * SS + k0 + kc * 32 + quad * 8);
        }
        #pragma unroll
        for (int qt = 0; qt < 2; ++qt)
            #pragma unroll
            for (int kc = 0; kc < 2; ++kc) {
                f32x4 z = {0.f, 0.f, 0.f, 0.f};
                f32x4 s0 = __builtin_amdgcn_mfma_f32_16x16x32_bf16(qa[qt], kb[kc][0], z, 0, 0, 0);
                f32x4 s1 = __builtin_amdgcn_mfma_f32_16x16x32_bf16(qa[qt], kb[kc][1], z, 0, 0, 0);
                #pragma unroll
                for (int r = 0; r < 4; ++r) {
                    float p0 = __builtin_amdgcn_exp2f(s0[r]);
                    float p1 = __builtin_amdgcn_exp2f(s1[r]);
                    lsum2[qt][r] += (f32x2){p0, p1};
                    *(unsigned int*)(&plds[qt * 2 + kc][(quad * 4 + r) * PS + 2 * l16]) =
                        packbf_perm(p0, p1);
                }
            }
        #pragma unroll
        for (int qt = 0; qt < 2; ++qt)
            #pragma unroll
            for (int kc = 0; kc < 2; ++kc) {
                bf16x8 pa = *(const bf16x8*)(&plds[qt * 2 + kc][l16 * PS + quad * 8]);
                o[qt][0] = __builtin_amdgcn_mfma_f32_16x16x32_bf16(pa, vb[kc][0], o[qt][0], 0, 0, 0);
                o[qt][1] = __builtin_amdgcn_mfma_f32_16x16x32_bf16(pa, vb[kc][1], o[qt][1], 0, 0, 0);
            }
    }
    float* poh = po + (size_t)half * POH;
    #pragma unroll
    for (int qt = 0; qt < 2; ++qt)
        #pragma unroll
        for (int r = 0; r < 4; ++r) {
            float s = lsum2[qt][r][0] + lsum2[qt][r][1];
            s += __shfl_xor(s, 1);
            s += __shfl_xor(s, 2);
            s += __shfl_xor(s, 4);
            s += __shfl_xor(s, 8);
            int qrow = q0 + qt * 16 + quad * 4 + r;
            size_t rowi = (size_t)bh * SS + qrow;
            poh[rowi * DHH + l16]      = o[qt][0][r];     // unnormalized
            poh[rowi * DHH + 16 + l16] = o[qt][1][r];
            if (l16 == 0) pl[(size_t)half * (BB * HH * SS) + rowi] = s;
        }
}

// combine: ob[b,s,h*DH+d] = (po0 + po1) / (l0 + l1), bf16
__global__ __launch_bounds__(256) void attn_combine(
    const float* __restrict__ po, const float* __restrict__ pl, unsigned short* __restrict__ ob)
{
    int tid = blockIdx.x * 256 + threadIdx.x;   // 1,048,576 threads, 4 dims each
    int row = tid >> 3;                          // bh*SS + q
    int d4 = (tid & 7) * 4;
    float inv = 1.f / (pl[row] + pl[BB * HH * SS + row]);
    float4 a = *(const float4*)(po + (size_t)row * DHH + d4);
    float4 b4 = *(const float4*)(po + POH + (size_t)row * DHH + d4);
    float o0 = (a.x + b4.x) * inv, o1 = (a.y + b4.y) * inv;
    float o2 = (a.z + b4.z) * inv, o3 = (a.w + b4.w) * inv;
    int bh = row >> 10, q = row & 1023, b = bh >> 3, h = bh & 7;
    unsigned short* dst = ob + ((size_t)b * SS + q) * DD + h * DHH + d4;
    uint2 w; w.x = packbf(o0, o1); w.y = packbf(o2, o3);
    *(uint2*)dst = w;
}

extern "C" void kernel_launch(void* const* d_in, const int* in_sizes, int n_in,
                              void* d_out, int out_size, void* d_ws, size_t ws_size,
                              hipStream_t stream)
{
    const float* x        = (const float*)d_in[0];
    const float* tok_w    = (const float*)d_in[1];
    const float* tok_b    = (const float*)d_in[2];
    const float* tnorm_g  = (const float*)d_in[3];
    const float* tnorm_b  = (const float*)d_in[4];
    const float* in_proj_w= (const float*)d_in[5];
    const float* in_proj_b= (const float*)d_in[6];
    const float* out_w    = (const float*)d_in[7];
    const float* out_b    = (const float*)d_in[8];
    const float* ln1_g    = (const float*)d_in[9];
    const float* ln1_b    = (const float*)d_in[10];
    const float* ln2_g    = (const float*)d_in[11];
    const float* ln2_b    = (const float*)d_in[12];
    const float* lin1_w   = (const float*)d_in[13];
    const float* lin1_b   = (const float*)d_in[14];
    const float* lin2_w   = (const float*)d_in[15];
    const float* lin2_b   = (const float*)d_in[16];
    const float* fnorm_g  = (const float*)d_in[17];
    const float* fnorm_b  = (const float*)d_in[18];

    char* ws = (char*)d_ws;
    unsigned short* wb        = (unsigned short*)ws;                 // 0 .. 6553600
    unsigned short* wb_tok    = wb;
    unsigned short* wb_inproj = wb + 131072;
    unsigned short* wb_out    = wb + 917504;
    unsigned short* wb_lin1   = wb + 1179648;
    unsigned short* wb_lin2   = wb + 2228224;
    unsigned short* qkvb = (unsigned short*)(ws + 6553600);          // 24 MB (6553600..31719424)
    unsigned short* xb   = qkvb;                                     // tokenize-only alias
    float*          pl   = (float*)(ws + 6553600);                   // attn lsum partials (1 MB);
                                                                     // lives in qkvb region: qkvb is
                                                                     // dead after rope, rewritten next
                                                                     // layer by the qkv GEMM.
    float*          h    = (float*)(ws + 31719424);                  // 16 MB fp32 residual
    unsigned short* y    = (unsigned short*)(ws + 48496640);         // 8 MB
    unsigned short* qr   = (unsigned short*)(ws + 56885248);         // 8 MB
    unsigned short* kr   = (unsigned short*)(ws + 65273856);         // 8 MB
    unsigned short* vt   = (unsigned short*)(ws + 73662464);         // 8 MB
    unsigned short* ob   = (unsigned short*)(ws + 82051072);         // 8 MB
    unsigned short* a1   = (unsigned short*)(ws + 90439680);         // 32 MB (exactly to ws end)
    float*          po   = (float*)(ws + 90439680);                  // attn O-partials (2 x 16 MB, dead a1)
    float*          t0   = (float*)(ws + 90439680);                  // tokenize out (pre-loop only)

    convert_weights<<<dim3(12800), dim3(256), 0, stream>>>(tok_w, in_proj_w, out_w, lin1_w, lin2_w, wb);
    convert_x<<<dim3(8192), dim3(256), 0, stream>>>((const float4*)x, (ushort4*)xb, MROWS * TT / 4);

    // tokenize: t0 = x @ tok_w^T + tok_b ; h = LN(t0)
    gemm_n64<0><<<dim3(DD/64, MROWS/128), dim3(256), 0, stream>>>(
        xb, wb_tok, tok_b, nullptr, t0, MROWS, DD, TT);
    ln_rows<0><<<dim3(MROWS/4), dim3(256), 0, stream>>>(t0, tnorm_g, tnorm_b, h);

    for (int i = 0; i < LL; ++i) {
        ln_rows<1><<<dim3(MROWS/4), dim3(256), 0, stream>>>(h, ln1_g + i*DD, ln1_b + i*DD, y);
        gemm_lds<128,0><<<dim3((3*DD)/128, MROWS/128), dim3(256), 0, stream>>>(
            y, wb_inproj + (size_t)i*3*DD*DD, in_proj_b + i*3*DD, qkvb, MROWS, 3*DD, DD);
        rope_kernel<<<dim3(MROWS), dim3(256), 0, stream>>>(qkvb, qr, kr, vt);
        attn_kernel<<<dim3(BB*HH, SS/32, 2), dim3(64), 0, stream>>>(qr, kr, vt, po, pl);
        attn_combine<<<dim3(4096), dim3(256), 0, stream>>>(po, pl, ob);
        gemm_n64<1><<<dim3(DD/64, MROWS/128), dim3(256), 0, stream>>>(
            ob, wb_out + (size_t)i*DD*DD, out_b + i*DD, h, h, MROWS, DD, DD);
        ln_rows<1><<<dim3(MROWS/4), dim3(256), 0, stream>>>(h, ln2_g + i*DD, ln2_b + i*DD, y);
        gemm_lds<256,1><<<dim3(FFN/256, MROWS/128), dim3(256), 0, stream>>>(
            y, wb_lin1 + (size_t)i*FFN*DD, lin1_b + i*FFN, a1, MROWS, FFN, DD);
        gemm_n64<1><<<dim3(DD/64, MROWS/128), dim3(256), 0, stream>>>(
            a1, wb_lin2 + (size_t)i*DD*FFN, lin2_b + i*DD, h, h, MROWS, DD, FFN);
    }
    ln_rows<0><<<dim3(MROWS/4), dim3(256), 0, stream>>>(h, fnorm_g, fnorm_b, (float*)d_out);
}

// Round 15
// 801.120 us; speedup vs baseline: 1.0991x; 1.0214x over previous
//
#include <hip/hip_runtime.h>

#define BB 16
#define SS 1024
#define TT 512
#define DD 256
#define HH 8
#define LL 4
#define FFN 1024
#define DHH 32
#define MROWS (BB*SS)   // 16384

typedef short bf16x8 __attribute__((ext_vector_type(8)));
typedef float f32x4 __attribute__((ext_vector_type(4)));
typedef float f32x2 __attribute__((ext_vector_type(2)));

__device__ __forceinline__ unsigned short f2bf(float f) {
    unsigned int u = __float_as_uint(f);
    unsigned int r = (u + 0x7fffu + ((u >> 16) & 1u)) >> 16;
    return (unsigned short)r;
}
__device__ __forceinline__ float bf2f(unsigned short h) {
    return __uint_as_float(((unsigned int)h) << 16);
}
__device__ __forceinline__ unsigned int packbf(float a, float b) {
    return (__float_as_uint(a) >> 16) | (__float_as_uint(b) & 0xffff0000u);
}
// one v_perm_b32: low16 = bf16trunc(p0), high16 = bf16trunc(p1)
__device__ __forceinline__ unsigned int packbf_perm(float p0, float p1) {
    return __builtin_amdgcn_perm(__float_as_uint(p1), __float_as_uint(p0), 0x07060302u);
}

// async global->LDS, 16B per lane. LDS dest must be wave-uniform base + lane*16.
__device__ __forceinline__ void g2l16(const unsigned short* g, unsigned short* l) {
    __builtin_amdgcn_global_load_lds(
        (const __attribute__((address_space(1))) unsigned int*)g,
        (__attribute__((address_space(3))) unsigned int*)l, 16, 0, 0);
}

// ---------------- weight conversion (fp32 -> bf16) ----------------
__global__ __launch_bounds__(256) void convert_weights(
    const float* __restrict__ w0, const float* __restrict__ w1, const float* __restrict__ w2,
    const float* __restrict__ w3, const float* __restrict__ w4, unsigned short* __restrict__ dst)
{
    int i = blockIdx.x * 256 + threadIdx.x;
    if (i >= 3276800) return;
    float v;
    if (i < 131072)        v = w0[i];
    else if (i < 917504)   v = w1[i - 131072];
    else if (i < 1179648)  v = w2[i - 917504];
    else if (i < 2228224)  v = w3[i - 1179648];
    else                   v = w4[i - 2228224];
    dst[i] = f2bf(v);
}

__global__ __launch_bounds__(256) void convert_x(const float4* __restrict__ x, ushort4* __restrict__ xb, int n4)
{
    int i = blockIdx.x * 256 + threadIdx.x;
    if (i >= n4) return;
    float4 v = x[i];
    ushort4 o;
    o.x = f2bf(v.x); o.y = f2bf(v.y); o.z = f2bf(v.z); o.w = f2bf(v.w);
    xb[i] = o;
}

// ---------------- wide GEMM (qkv / lin1): 128 x BN block, BK=32, permuted-B wide epilogue ----------------
template<int BN, int RELU>
__global__ __launch_bounds__(256, 2) void gemm_lds(
    const unsigned short* __restrict__ A, const unsigned short* __restrict__ Bw,
    const float* __restrict__ bias, void* out, int M, int N, int K)
{
    constexpr int NJ = BN / 32;
    __shared__ __align__(16) unsigned short sA[2][128 * 32];
    __shared__ __align__(16) unsigned short sB[2][BN * 32];
    const int t = threadIdx.x;
    const int lane = t & 63, quad = lane >> 4, l16 = lane & 15;
    const int wave = t >> 6, wm = wave >> 1, wn = wave & 1;
    const int row0 = blockIdx.y * 128, col0 = blockIdx.x * BN;

    const unsigned short* gA = A + (size_t)(row0 + (t >> 2)) * K + (t & 3) * 8;
    const size_t rstep = (size_t)64 * K;
    const unsigned short* gBp[BN / 64];
    #pragma unroll
    for (int p = 0; p < BN / 64; ++p) {
        int l = p * 64 + (t >> 2);
        int wrow = (l & (16 * NJ)) + (l & 15) * NJ + ((l >> 4) & (NJ - 1));
        gBp[p] = Bw + (size_t)(col0 + wrow) * K + (t & 3) * 8;
    }

    f32x4 acc[4][NJ];
    #pragma unroll
    for (int i = 0; i < 4; ++i)
        #pragma unroll
        for (int j = 0; j < NJ; ++j)
            acc[i][j] = (f32x4){0.f, 0.f, 0.f, 0.f};

    g2l16(gA, &sA[0][t * 8]);
    g2l16(gA + rstep, &sA[0][(t + 256) * 8]);
    #pragma unroll
    for (int p = 0; p < BN / 64; ++p)
        g2l16(gBp[p], &sB[0][p * 2048 + t * 8]);

    for (int k0 = 0; k0 < K; k0 += 32) {
        const int cur = (k0 >> 5) & 1;
        __syncthreads();
        if (k0 + 32 < K) {
            const int nxt = cur ^ 1;
            g2l16(gA + k0 + 32, &sA[nxt][t * 8]);
            g2l16(gA + rstep + k0 + 32, &sA[nxt][(t + 256) * 8]);
            #pragma unroll
            for (int p = 0; p < BN / 64; ++p)
                g2l16(gBp[p] + k0 + 32, &sB[nxt][p * 2048 + t * 8]);
        }
        bf16x8 a[4], b[NJ];
        #pragma unroll
        for (int i = 0; i < 4; ++i)
            a[i] = *(const bf16x8*)(&sA[cur][(wm * 64 + i * 16 + l16) * 32 + quad * 8]);
        #pragma unroll
        for (int j = 0; j < NJ; ++j)
            b[j] = *(const bf16x8*)(&sB[cur][(wn * (BN / 2) + j * 16 + l16) * 32 + quad * 8]);
        #pragma unroll
        for (int i = 0; i < 4; ++i)
            #pragma unroll
            for (int j = 0; j < NJ; ++j)
                acc[i][j] = __builtin_amdgcn_mfma_f32_16x16x32_bf16(a[i], b[j], acc[i][j], 0, 0, 0);
    }

    const int colbase = col0 + wn * (BN / 2) + l16 * NJ;
    float bb[NJ];
    #pragma unroll
    for (int j = 0; j < NJ; ++j) bb[j] = bias[colbase + j];
    #pragma unroll
    for (int i = 0; i < 4; ++i) {
        #pragma unroll
        for (int r = 0; r < 4; ++r) {
            int row = row0 + wm * 64 + i * 16 + quad * 4 + r;
            float v[NJ];
            #pragma unroll
            for (int j = 0; j < NJ; ++j) {
                v[j] = acc[i][j][r] + bb[j];
                if (RELU) v[j] = fmaxf(v[j], 0.f);
            }
            unsigned short* dst = (unsigned short*)out + (size_t)row * N + colbase;
            if constexpr (NJ == 4) {
                uint2 w; w.x = packbf(v[0], v[1]); w.y = packbf(v[2], v[3]);
                *(uint2*)dst = w;
            } else {
                uint4 w; w.x = packbf(v[0], v[1]); w.y = packbf(v[2], v[3]);
                w.z = packbf(v[4], v[5]); w.w = packbf(v[6], v[7]);
                *(uint4*)dst = w;
            }
        }
    }
}

// ---------------- N=64-col GEMM (tokenize / out-proj / lin2): 128 x 64 block, BK=64 ----------------
template<int RESID>
__global__ __launch_bounds__(256, 2) void gemm_n64(
    const unsigned short* __restrict__ A, const unsigned short* __restrict__ Bw,
    const float* __restrict__ bias, const float* resid, float* out, int M, int N, int K)
{
    __shared__ __align__(16) unsigned short sA[2][2 * 128 * 32];   // [buf][kh][row][32]
    __shared__ __align__(16) unsigned short sB[2][2 * 64 * 32];
    const int t = threadIdx.x;
    const int lane = t & 63, quad = lane >> 4, l16 = lane & 15;
    const int wave = t >> 6, wm = wave >> 1, wn = wave & 1;
    const int row0 = blockIdx.y * 128, col0 = blockIdx.x * 64;

    const unsigned short* gA = A + (size_t)(row0 + (t >> 2)) * K + (t & 3) * 8;
    const size_t rstep = (size_t)64 * K;
    const int bl = t >> 2;
    const unsigned short* gB = Bw + (size_t)(col0 + (bl & 32) + (bl & 15) * 2 + ((bl >> 4) & 1)) * K + (t & 3) * 8;

    f32x4 acc[4][2];
    #pragma unroll
    for (int i = 0; i < 4; ++i) {
        acc[i][0] = (f32x4){0.f, 0.f, 0.f, 0.f};
        acc[i][1] = (f32x4){0.f, 0.f, 0.f, 0.f};
    }

    auto stage = [&](int k0, int buf) {
        #pragma unroll
        for (int kh = 0; kh < 2; ++kh) {
            #pragma unroll
            for (int rh = 0; rh < 2; ++rh)
                g2l16(gA + (size_t)rh * rstep + k0 + kh * 32,
                      &sA[buf][kh * 4096 + rh * 2048 + t * 8]);
            g2l16(gB + k0 + kh * 32, &sB[buf][kh * 2048 + t * 8]);
        }
    };

    stage(0, 0);
    for (int k0 = 0; k0 < K; k0 += 64) {
        const int cur = (k0 >> 6) & 1;
        __syncthreads();
        if (k0 + 64 < K) stage(k0 + 64, cur ^ 1);
        #pragma unroll
        for (int kh = 0; kh < 2; ++kh) {
            bf16x8 a[4], b[2];
            #pragma unroll
            for (int i = 0; i < 4; ++i)
                a[i] = *(const bf16x8*)(&sA[cur][kh * 4096 + wm * 2048 + (i * 16 + l16) * 32 + quad * 8]);
            b[0] = *(const bf16x8*)(&sB[cur][kh * 2048 + (wn * 32 + l16) * 32 + quad * 8]);
            b[1] = *(const bf16x8*)(&sB[cur][kh * 2048 + (wn * 32 + 16 + l16) * 32 + quad * 8]);
            #pragma unroll
            for (int i = 0; i < 4; ++i) {
                acc[i][0] = __builtin_amdgcn_mfma_f32_16x16x32_bf16(a[i], b[0], acc[i][0], 0, 0, 0);
                acc[i][1] = __builtin_amdgcn_mfma_f32_16x16x32_bf16(a[i], b[1], acc[i][1], 0, 0, 0);
            }
        }
    }

    const int colbase = col0 + wn * 32 + l16 * 2;
    float b0 = bias[colbase], b1 = bias[colbase + 1];
    #pragma unroll
    for (int i = 0; i < 4; ++i) {
        #pragma unroll
        for (int r = 0; r < 4; ++r) {
            int row = row0 + wm * 64 + i * 16 + quad * 4 + r;
            float2 o;
            o.x = acc[i][0][r] + b0;
            o.y = acc[i][1][r] + b1;
            if (RESID) {
                float2 rv = *(const float2*)(resid + (size_t)row * N + colbase);
                o.x += rv.x; o.y += rv.y;
            }
            *(float2*)(out + (size_t)row * N + colbase) = o;
        }
    }
}

// ---------------- LayerNorm over D=256, one wave per row, 4 rows/block, float4 loads ----------------
template<int OUT_BF16>
__global__ __launch_bounds__(256) void ln_rows(const float* __restrict__ in,
    const float* __restrict__ g, const float* __restrict__ bt, void* __restrict__ out)
{
    int wave = threadIdx.x >> 6, lane = threadIdx.x & 63;
    size_t row = (size_t)blockIdx.x * 4 + wave;
    float4 v = ((const float4*)(in + row * DD))[lane];
    float s = v.x + v.y + v.z + v.w;
    #pragma unroll
    for (int m = 32; m >= 1; m >>= 1) s += __shfl_xor(s, m);
    float mean = s * (1.f / DD);
    float dx = v.x - mean, dy = v.y - mean, dz = v.z - mean, dw = v.w - mean;
    float ss = dx * dx + dy * dy + dz * dz + dw * dw;
    #pragma unroll
    for (int m = 32; m >= 1; m >>= 1) ss += __shfl_xor(ss, m);
    float inv = rsqrtf(ss * (1.f / DD) + 1e-5f);
    float4 gv = ((const float4*)g)[lane];
    float4 bv = ((const float4*)bt)[lane];
    float ox = dx * inv * gv.x + bv.x, oy = dy * inv * gv.y + bv.y;
    float oz = dz * inv * gv.z + bv.z, ow = dw * inv * gv.w + bv.w;
    if (OUT_BF16) {
        ushort4 o; o.x = f2bf(ox); o.y = f2bf(oy); o.z = f2bf(oz); o.w = f2bf(ow);
        ((ushort4*)((unsigned short*)out + row * DD))[lane] = o;
    } else {
        ((float4*)((float*)out + row * DD))[lane] = (float4){ox, oy, oz, ow};
    }
}

// ---------------- RoPE + layout (kr even/odd interleaved per 32-chunk) ----------------
__global__ __launch_bounds__(256) void rope_kernel(const unsigned short* __restrict__ qkv,
    unsigned short* __restrict__ qr, unsigned short* __restrict__ kr, unsigned short* __restrict__ vt)
{
    __shared__ float sc[2][16];
    int row = blockIdx.x;          // b*S + s
    int t = threadIdx.x;           // h*32 + d
    int h = t >> 5, d = t & 31, j = d & 15;
    int b = row >> 10, s = row & 1023;
    if (t < 16) {
        float inv_freq = __expf(-(float)t * 0.575646273248511f);  // 10000^(-t/16)
        float fr = (float)s * inv_freq;
        float c, sn;
        __sincosf(fr, &sn, &c);
        sc[0][t] = c;
        sc[1][t] = sn;
    }
    const unsigned short* rp = qkv + (size_t)row * 768;
    float qv = bf2f(rp[t]);
    float kv = bf2f(rp[256 + t]);
    float vv = bf2f(rp[512 + t]);
    __syncthreads();
    float c = sc[0][j], sn = sc[1][j];
    float qp = __shfl_xor(qv, 16);
    float kp = __shfl_xor(kv, 16);
    const float qscale = 1.4426950408889634f / 5.656854249492381f;  // log2e/sqrt(32)
    float rq = (qv * c + ((d < 16) ? -qp : qp) * sn) * qscale;
    float rk = kv * c + ((d < 16) ? -kp : kp) * sn;
    int bh = (b << 3) | h;
    qr[((size_t)bh * SS + s) * DHH + d] = f2bf(rq);
    int jj = s & 31;
    int sp = (s & ~31) | (((jj & 1) << 4) | (jj >> 1));   // even/odd interleave
    kr[((size_t)bh * SS + sp) * DHH + d] = f2bf(rk);
    vt[((size_t)bh * DHH + d) * SS + s] = f2bf(vv);
}

// ---------------- fused attention: round-11 core + register-double-buffered K/V prefetch ----------------
// 1 wave/block, 2x16-query tiles, 64 keys/iter, 4 indep exp->LDS->PV chains.
// K/V loads for iteration i+1 are ISSUED before compute(i): a full compute phase hides
// the ~200-cyc L2 latency that previously stalled each iteration's first MFMA.
#define PS 40   // P-tile LDS row stride (u16)
__global__ __launch_bounds__(64) void attn_kernel(
    const unsigned short* __restrict__ qr, const unsigned short* __restrict__ kr,
    const unsigned short* __restrict__ vt, unsigned short* __restrict__ ob)
{
    __shared__ __align__(16) unsigned short plds[4][16 * PS];  // [qt*2+kc], 5 KB
    int lane = threadIdx.x;
    int quad = lane >> 4, l16 = lane & 15;
    int bh = blockIdx.x;
    int q0 = blockIdx.y * 32;
    int b = bh >> 3, h = bh & 7;
    const unsigned short* qbase = qr + ((size_t)bh * SS + q0) * DHH;
    const unsigned short* kbase = kr + (size_t)bh * SS * DHH;
    const unsigned short* vbase = vt + (size_t)bh * DHH * SS;
    bf16x8 qa[2];
    qa[0] = *(const bf16x8*)(qbase + (size_t)l16 * DHH + quad * 8);
    qa[1] = *(const bf16x8*)(qbase + (size_t)(16 + l16) * DHH + quad * 8);
    f32x4 o[2][2] = {};
    f32x2 lsum2[2][4] = {};

    bf16x8 kbA[2][2], vbA[2][2], kbB[2][2], vbB[2][2];

    auto loadKV = [&](int k0, bf16x8 (&kb)[2][2], bf16x8 (&vb)[2][2]) {
        #pragma unroll
        for (int kc = 0; kc < 2; ++kc) {
            const unsigned short* kp = kbase + (size_t)(k0 + kc * 32) * DHH;
            kb[kc][0] = *(const bf16x8*)(kp + (size_t)l16 * DHH + quad * 8);        // even keys
            kb[kc][1] = *(const bf16x8*)(kp + (size_t)(16 + l16) * DHH + quad * 8); // odd keys
            vb[kc][0] = *(const bf16x8*)(vbase + (size_t)l16 * SS + k0 + kc * 32 + quad * 8);
            vb[kc][1] = *(const bf16x8*)(vbase + (size_t)(l16 + 16) * SS + k0 + kc * 32 + quad * 8);
        }
    };
    auto compute = [&](bf16x8 (&kb)[2][2], bf16x8 (&vb)[2][2]) {
        #pragma unroll
        for (int qt = 0; qt < 2; ++qt)
            #pragma unroll
            for (int kc = 0; kc < 2; ++kc) {
                f32x4 z = {0.f, 0.f, 0.f, 0.f};
                f32x4 s0 = __builtin_amdgcn_mfma_f32_16x16x32_bf16(qa[qt], kb[kc][0], z, 0, 0, 0);
                f32x4 s1 = __builtin_amdgcn_mfma_f32_16x16x32_bf16(qa[qt], kb[kc][1], z, 0, 0, 0);
                #pragma unroll
                for (int r = 0; r < 4; ++r) {
                    float p0 = __builtin_amdgcn_exp2f(s0[r]);
                    float p1 = __builtin_amdgcn_exp2f(s1[r]);
                    lsum2[qt][r] += (f32x2){p0, p1};
                    *(unsigned int*)(&plds[qt * 2 + kc][(quad * 4 + r) * PS + 2 * l16]) =
                        packbf_perm(p0, p1);
                }
            }
        #pragma unroll
        for (int qt = 0; qt < 2; ++qt)
            #pragma unroll
            for (int kc = 0; kc < 2; ++kc) {
                bf16x8 pa = *(const bf16x8*)(&plds[qt * 2 + kc][l16 * PS + quad * 8]);
                o[qt][0] = __builtin_amdgcn_mfma_f32_16x16x32_bf16(pa, vb[kc][0], o[qt][0], 0, 0, 0);
                o[qt][1] = __builtin_amdgcn_mfma_f32_16x16x32_bf16(pa, vb[kc][1], o[qt][1], 0, 0, 0);
            }
    };

    loadKV(0, kbA, vbA);
    for (int k0 = 0; k0 < SS; k0 += 128) {
        loadKV(k0 + 64, kbB, vbB);          // prefetch while computing A
        compute(kbA, vbA);
        if (k0 + 128 < SS)
            loadKV(k0 + 128, kbA, vbA);     // prefetch while computing B
        compute(kbB, vbB);
    }

    #pragma unroll
    for (int qt = 0; qt < 2; ++qt)
        #pragma unroll
        for (int r = 0; r < 4; ++r) {
            float s = lsum2[qt][r][0] + lsum2[qt][r][1];
            s += __shfl_xor(s, 1);
            s += __shfl_xor(s, 2);
            s += __shfl_xor(s, 4);
            s += __shfl_xor(s, 8);
            float inv = 1.f / s;
            int qrow = q0 + qt * 16 + quad * 4 + r;
            size_t base = ((size_t)b * SS + qrow) * DD + h * DHH;
            ob[base + l16]      = f2bf(o[qt][0][r] * inv);
            ob[base + 16 + l16] = f2bf(o[qt][1][r] * inv);
        }
}

extern "C" void kernel_launch(void* const* d_in, const int* in_sizes, int n_in,
                              void* d_out, int out_size, void* d_ws, size_t ws_size,
                              hipStream_t stream)
{
    const float* x        = (const float*)d_in[0];
    const float* tok_w    = (const float*)d_in[1];
    const float* tok_b    = (const float*)d_in[2];
    const float* tnorm_g  = (const float*)d_in[3];
    const float* tnorm_b  = (const float*)d_in[4];
    const float* in_proj_w= (const float*)d_in[5];
    const float* in_proj_b= (const float*)d_in[6];
    const float* out_w    = (const float*)d_in[7];
    const float* out_b    = (const float*)d_in[8];
    const float* ln1_g    = (const float*)d_in[9];
    const float* ln1_b    = (const float*)d_in[10];
    const float* ln2_g    = (const float*)d_in[11];
    const float* ln2_b    = (const float*)d_in[12];
    const float* lin1_w   = (const float*)d_in[13];
    const float* lin1_b   = (const float*)d_in[14];
    const float* lin2_w   = (const float*)d_in[15];
    const float* lin2_b   = (const float*)d_in[16];
    const float* fnorm_g  = (const float*)d_in[17];
    const float* fnorm_b  = (const float*)d_in[18];

    char* ws = (char*)d_ws;
    unsigned short* wb        = (unsigned short*)ws;
    unsigned short* wb_tok    = wb;
    unsigned short* wb_inproj = wb + 131072;
    unsigned short* wb_out    = wb + 917504;
    unsigned short* wb_lin1   = wb + 1179648;
    unsigned short* wb_lin2   = wb + 2228224;
    unsigned short* qkvb = (unsigned short*)(ws + 6553600);
    unsigned short* xb   = qkvb;                                     // tokenize-only alias
    float*          h    = (float*)(ws + 31719424);
    unsigned short* y    = (unsigned short*)(ws + 48496640);
    unsigned short* qr   = (unsigned short*)(ws + 56885248);
    unsigned short* kr   = (unsigned short*)(ws + 65273856);
    unsigned short* vt   = (unsigned short*)(ws + 73662464);
    unsigned short* ob   = (unsigned short*)(ws + 82051072);
    unsigned short* a1   = (unsigned short*)(ws + 90439680);
    float*          t0   = (float*)(ws + 90439680);                  // aliases a1 (pre-layer only)

    convert_weights<<<dim3(12800), dim3(256), 0, stream>>>(tok_w, in_proj_w, out_w, lin1_w, lin2_w, wb);
    convert_x<<<dim3(8192), dim3(256), 0, stream>>>((const float4*)x, (ushort4*)xb, MROWS * TT / 4);

    // tokenize: t0 = x @ tok_w^T + tok_b ; h = LN(t0)
    gemm_n64<0><<<dim3(DD/64, MROWS/128), dim3(256), 0, stream>>>(
        xb, wb_tok, tok_b, nullptr, t0, MROWS, DD, TT);
    ln_rows<0><<<dim3(MROWS/4), dim3(256), 0, stream>>>(t0, tnorm_g, tnorm_b, h);

    for (int i = 0; i < LL; ++i) {
        ln_rows<1><<<dim3(MROWS/4), dim3(256), 0, stream>>>(h, ln1_g + i*DD, ln1_b + i*DD, y);
        gemm_lds<128,0><<<dim3((3*DD)/128, MROWS/128), dim3(256), 0, stream>>>(
            y, wb_inproj + (size_t)i*3*DD*DD, in_proj_b + i*3*DD, qkvb, MROWS, 3*DD, DD);
        rope_kernel<<<dim3(MROWS), dim3(256), 0, stream>>>(qkvb, qr, kr, vt);
        attn_kernel<<<dim3(BB*HH, SS/32), dim3(64), 0, stream>>>(qr, kr, vt, ob);
        gemm_n64<1><<<dim3(DD/64, MROWS/128), dim3(256), 0, stream>>>(
            ob, wb_out + (size_t)i*DD*DD, out_b + i*DD, h, h, MROWS, DD, DD);
        ln_rows<1><<<dim3(MROWS/4), dim3(256), 0, stream>>>(h, ln2_g + i*DD, ln2_b + i*DD, y);
        gemm_lds<256,1><<<dim3(FFN/256, MROWS/128), dim3(256), 0, stream>>>(
            y, wb_lin1 + (size_t)i*FFN*DD, lin1_b + i*FFN, a1, MROWS, FFN, DD);
        gemm_n64<1><<<dim3(DD/64, MROWS/128), dim3(256), 0, stream>>>(
            a1, wb_lin2 + (size_t)i*DD*FFN, lin2_b + i*DD, h, h, MROWS, DD, FFN);
    }
    ln_rows<0><<<dim3(MROWS/4), dim3(256), 0, stream>>>(h, fnorm_g, fnorm_b, (float*)d_out);
}

// Round 16
// 780.868 us; speedup vs baseline: 1.1276x; 1.0259x over previous
//
#include <hip/hip_runtime.h>

#define BB 16
#define SS 1024
#define TT 512
#define DD 256
#define HH 8
#define LL 4
#define FFN 1024
#define DHH 32
#define MROWS (BB*SS)   // 16384

typedef short bf16x8 __attribute__((ext_vector_type(8)));
typedef float f32x4 __attribute__((ext_vector_type(4)));
typedef float f32x2 __attribute__((ext_vector_type(2)));

__device__ __forceinline__ unsigned short f2bf(float f) {
    unsigned int u = __float_as_uint(f);
    unsigned int r = (u + 0x7fffu + ((u >> 16) & 1u)) >> 16;
    return (unsigned short)r;
}
__device__ __forceinline__ float bf2f(unsigned short h) {
    return __uint_as_float(((unsigned int)h) << 16);
}
__device__ __forceinline__ unsigned int packbf(float a, float b) {
    return (__float_as_uint(a) >> 16) | (__float_as_uint(b) & 0xffff0000u);
}
// one v_perm_b32: low16 = bf16trunc(p0), high16 = bf16trunc(p1)
__device__ __forceinline__ unsigned int packbf_perm(float p0, float p1) {
    return __builtin_amdgcn_perm(__float_as_uint(p1), __float_as_uint(p0), 0x07060302u);
}

// async global->LDS, 16B per lane. LDS dest must be wave-uniform base + lane*16.
__device__ __forceinline__ void g2l16(const unsigned short* g, unsigned short* l) {
    __builtin_amdgcn_global_load_lds(
        (const __attribute__((address_space(1))) unsigned int*)g,
        (__attribute__((address_space(3))) unsigned int*)l, 16, 0, 0);
}

// ---------------- weight conversion (fp32 -> bf16) ----------------
__global__ __launch_bounds__(256) void convert_weights(
    const float* __restrict__ w0, const float* __restrict__ w1, const float* __restrict__ w2,
    const float* __restrict__ w3, const float* __restrict__ w4, unsigned short* __restrict__ dst)
{
    int i = blockIdx.x * 256 + threadIdx.x;
    if (i >= 3276800) return;
    float v;
    if (i < 131072)        v = w0[i];
    else if (i < 917504)   v = w1[i - 131072];
    else if (i < 1179648)  v = w2[i - 917504];
    else if (i < 2228224)  v = w3[i - 1179648];
    else                   v = w4[i - 2228224];
    dst[i] = f2bf(v);
}

__global__ __launch_bounds__(256) void convert_x(const float4* __restrict__ x, ushort4* __restrict__ xb, int n4)
{
    int i = blockIdx.x * 256 + threadIdx.x;
    if (i >= n4) return;
    float4 v = x[i];
    ushort4 o;
    o.x = f2bf(v.x); o.y = f2bf(v.y); o.z = f2bf(v.z); o.w = f2bf(v.w);
    xb[i] = o;
}

// ---------------- wide GEMM (qkv / lin1): 128 x BN block, BK=32, permuted-B wide epilogue ----------------
template<int BN, int RELU>
__global__ __launch_bounds__(256, 2) void gemm_lds(
    const unsigned short* __restrict__ A, const unsigned short* __restrict__ Bw,
    const float* __restrict__ bias, void* out, int M, int N, int K)
{
    constexpr int NJ = BN / 32;
    __shared__ __align__(16) unsigned short sA[2][128 * 32];
    __shared__ __align__(16) unsigned short sB[2][BN * 32];
    const int t = threadIdx.x;
    const int lane = t & 63, quad = lane >> 4, l16 = lane & 15;
    const int wave = t >> 6, wm = wave >> 1, wn = wave & 1;
    const int row0 = blockIdx.y * 128, col0 = blockIdx.x * BN;

    const unsigned short* gA = A + (size_t)(row0 + (t >> 2)) * K + (t & 3) * 8;
    const size_t rstep = (size_t)64 * K;
    const unsigned short* gBp[BN / 64];
    #pragma unroll
    for (int p = 0; p < BN / 64; ++p) {
        int l = p * 64 + (t >> 2);
        int wrow = (l & (16 * NJ)) + (l & 15) * NJ + ((l >> 4) & (NJ - 1));
        gBp[p] = Bw + (size_t)(col0 + wrow) * K + (t & 3) * 8;
    }

    f32x4 acc[4][NJ];
    #pragma unroll
    for (int i = 0; i < 4; ++i)
        #pragma unroll
        for (int j = 0; j < NJ; ++j)
            acc[i][j] = (f32x4){0.f, 0.f, 0.f, 0.f};

    g2l16(gA, &sA[0][t * 8]);
    g2l16(gA + rstep, &sA[0][(t + 256) * 8]);
    #pragma unroll
    for (int p = 0; p < BN / 64; ++p)
        g2l16(gBp[p], &sB[0][p * 2048 + t * 8]);

    for (int k0 = 0; k0 < K; k0 += 32) {
        const int cur = (k0 >> 5) & 1;
        __syncthreads();
        if (k0 + 32 < K) {
            const int nxt = cur ^ 1;
            g2l16(gA + k0 + 32, &sA[nxt][t * 8]);
            g2l16(gA + rstep + k0 + 32, &sA[nxt][(t + 256) * 8]);
            #pragma unroll
            for (int p = 0; p < BN / 64; ++p)
                g2l16(gBp[p] + k0 + 32, &sB[nxt][p * 2048 + t * 8]);
        }
        bf16x8 a[4], b[NJ];
        #pragma unroll
        for (int i = 0; i < 4; ++i)
            a[i] = *(const bf16x8*)(&sA[cur][(wm * 64 + i * 16 + l16) * 32 + quad * 8]);
        #pragma unroll
        for (int j = 0; j < NJ; ++j)
            b[j] = *(const bf16x8*)(&sB[cur][(wn * (BN / 2) + j * 16 + l16) * 32 + quad * 8]);
        #pragma unroll
        for (int i = 0; i < 4; ++i)
            #pragma unroll
            for (int j = 0; j < NJ; ++j)
                acc[i][j] = __builtin_amdgcn_mfma_f32_16x16x32_bf16(a[i], b[j], acc[i][j], 0, 0, 0);
    }

    const int colbase = col0 + wn * (BN / 2) + l16 * NJ;
    float bb[NJ];
    #pragma unroll
    for (int j = 0; j < NJ; ++j) bb[j] = bias[colbase + j];
    #pragma unroll
    for (int i = 0; i < 4; ++i) {
        #pragma unroll
        for (int r = 0; r < 4; ++r) {
            int row = row0 + wm * 64 + i * 16 + quad * 4 + r;
            float v[NJ];
            #pragma unroll
            for (int j = 0; j < NJ; ++j) {
                v[j] = acc[i][j][r] + bb[j];
                if (RELU) v[j] = fmaxf(v[j], 0.f);
            }
            unsigned short* dst = (unsigned short*)out + (size_t)row * N + colbase;
            if constexpr (NJ == 4) {
                uint2 w; w.x = packbf(v[0], v[1]); w.y = packbf(v[2], v[3]);
                *(uint2*)dst = w;
            } else {
                uint4 w; w.x = packbf(v[0], v[1]); w.y = packbf(v[2], v[3]);
                w.z = packbf(v[4], v[5]); w.w = packbf(v[6], v[7]);
                *(uint4*)dst = w;
            }
        }
    }
}

// ---------------- N=64-col GEMM (tokenize / out-proj / lin2): 128 x 64 block, BK=64 ----------------
template<int RESID>
__global__ __launch_bounds__(256, 2) void gemm_n64(
    const unsigned short* __restrict__ A, const unsigned short* __restrict__ Bw,
    const float* __restrict__ bias, const float* resid, float* out, int M, int N, int K)
{
    __shared__ __align__(16) unsigned short sA[2][2 * 128 * 32];   // [buf][kh][row][32]
    __shared__ __align__(16) unsigned short sB[2][2 * 64 * 32];
    const int t = threadIdx.x;
    const int lane = t & 63, quad = lane >> 4, l16 = lane & 15;
    const int wave = t >> 6, wm = wave >> 1, wn = wave & 1;
    const int row0 = blockIdx.y * 128, col0 = blockIdx.x * 64;

    const unsigned short* gA = A + (size_t)(row0 + (t >> 2)) * K + (t & 3) * 8;
    const size_t rstep = (size_t)64 * K;
    const int bl = t >> 2;
    const unsigned short* gB = Bw + (size_t)(col0 + (bl & 32) + (bl & 15) * 2 + ((bl >> 4) & 1)) * K + (t & 3) * 8;

    f32x4 acc[4][2];
    #pragma unroll
    for (int i = 0; i < 4; ++i) {
        acc[i][0] = (f32x4){0.f, 0.f, 0.f, 0.f};
        acc[i][1] = (f32x4){0.f, 0.f, 0.f, 0.f};
    }

    auto stage = [&](int k0, int buf) {
        #pragma unroll
        for (int kh = 0; kh < 2; ++kh) {
            #pragma unroll
            for (int rh = 0; rh < 2; ++rh)
                g2l16(gA + (size_t)rh * rstep + k0 + kh * 32,
                      &sA[buf][kh * 4096 + rh * 2048 + t * 8]);
            g2l16(gB + k0 + kh * 32, &sB[buf][kh * 2048 + t * 8]);
        }
    };

    stage(0, 0);
    for (int k0 = 0; k0 < K; k0 += 64) {
        const int cur = (k0 >> 6) & 1;
        __syncthreads();
        if (k0 + 64 < K) stage(k0 + 64, cur ^ 1);
        #pragma unroll
        for (int kh = 0; kh < 2; ++kh) {
            bf16x8 a[4], b[2];
            #pragma unroll
            for (int i = 0; i < 4; ++i)
                a[i] = *(const bf16x8*)(&sA[cur][kh * 4096 + wm * 2048 + (i * 16 + l16) * 32 + quad * 8]);
            b[0] = *(const bf16x8*)(&sB[cur][kh * 2048 + (wn * 32 + l16) * 32 + quad * 8]);
            b[1] = *(const bf16x8*)(&sB[cur][kh * 2048 + (wn * 32 + 16 + l16) * 32 + quad * 8]);
            #pragma unroll
            for (int i = 0; i < 4; ++i) {
                acc[i][0] = __builtin_amdgcn_mfma_f32_16x16x32_bf16(a[i], b[0], acc[i][0], 0, 0, 0);
                acc[i][1] = __builtin_amdgcn_mfma_f32_16x16x32_bf16(a[i], b[1], acc[i][1], 0, 0, 0);
            }
        }
    }

    const int colbase = col0 + wn * 32 + l16 * 2;
    float b0 = bias[colbase], b1 = bias[colbase + 1];
    #pragma unroll
    for (int i = 0; i < 4; ++i) {
        #pragma unroll
        for (int r = 0; r < 4; ++r) {
            int row = row0 + wm * 64 + i * 16 + quad * 4 + r;
            float2 o;
            o.x = acc[i][0][r] + b0;
            o.y = acc[i][1][r] + b1;
            if (RESID) {
                float2 rv = *(const float2*)(resid + (size_t)row * N + colbase);
                o.x += rv.x; o.y += rv.y;
            }
            *(float2*)(out + (size_t)row * N + colbase) = o;
        }
    }
}

// ---------------- LayerNorm over D=256, one wave per row, 4 rows/block, float4 loads ----------------
template<int OUT_BF16>
__global__ __launch_bounds__(256) void ln_rows(const float* __restrict__ in,
    const float* __restrict__ g, const float* __restrict__ bt, void* __restrict__ out)
{
    int wave = threadIdx.x >> 6, lane = threadIdx.x & 63;
    size_t row = (size_t)blockIdx.x * 4 + wave;
    float4 v = ((const float4*)(in + row * DD))[lane];
    float s = v.x + v.y + v.z + v.w;
    #pragma unroll
    for (int m = 32; m >= 1; m >>= 1) s += __shfl_xor(s, m);
    float mean = s * (1.f / DD);
    float dx = v.x - mean, dy = v.y - mean, dz = v.z - mean, dw = v.w - mean;
    float ss = dx * dx + dy * dy + dz * dz + dw * dw;
    #pragma unroll
    for (int m = 32; m >= 1; m >>= 1) ss += __shfl_xor(ss, m);
    float inv = rsqrtf(ss * (1.f / DD) + 1e-5f);
    float4 gv = ((const float4*)g)[lane];
    float4 bv = ((const float4*)bt)[lane];
    float ox = dx * inv * gv.x + bv.x, oy = dy * inv * gv.y + bv.y;
    float oz = dz * inv * gv.z + bv.z, ow = dw * inv * gv.w + bv.w;
    if (OUT_BF16) {
        ushort4 o; o.x = f2bf(ox); o.y = f2bf(oy); o.z = f2bf(oz); o.w = f2bf(ow);
        ((ushort4*)((unsigned short*)out + row * DD))[lane] = o;
    } else {
        ((float4*)((float*)out + row * DD))[lane] = (float4){ox, oy, oz, ow};
    }
}

// ---------------- RoPE + layout (kr even/odd interleaved per 32-chunk) ----------------
__global__ __launch_bounds__(256) void rope_kernel(const unsigned short* __restrict__ qkv,
    unsigned short* __restrict__ qr, unsigned short* __restrict__ kr, unsigned short* __restrict__ vt)
{
    __shared__ float sc[2][16];
    int row = blockIdx.x;          // b*S + s
    int t = threadIdx.x;           // h*32 + d
    int h = t >> 5, d = t & 31, j = d & 15;
    int b = row >> 10, s = row & 1023;
    if (t < 16) {
        float inv_freq = __expf(-(float)t * 0.575646273248511f);  // 10000^(-t/16)
        float fr = (float)s * inv_freq;
        float c, sn;
        __sincosf(fr, &sn, &c);
        sc[0][t] = c;
        sc[1][t] = sn;
    }
    const unsigned short* rp = qkv + (size_t)row * 768;
    float qv = bf2f(rp[t]);
    float kv = bf2f(rp[256 + t]);
    float vv = bf2f(rp[512 + t]);
    __syncthreads();
    float c = sc[0][j], sn = sc[1][j];
    float qp = __shfl_xor(qv, 16);
    float kp = __shfl_xor(kv, 16);
    const float qscale = 1.4426950408889634f / 5.656854249492381f;  // log2e/sqrt(32)
    float rq = (qv * c + ((d < 16) ? -qp : qp) * sn) * qscale;
    float rk = kv * c + ((d < 16) ? -kp : kp) * sn;
    int bh = (b << 3) | h;
    qr[((size_t)bh * SS + s) * DHH + d] = f2bf(rq);
    int jj = s & 31;
    int sp = (s & ~31) | (((jj & 1) << 4) | (jj >> 1));   // even/odd interleave
    kr[((size_t)bh * SS + sp) * DHH + d] = f2bf(rk);
    vt[((size_t)bh * DHH + d) * SS + s] = f2bf(vv);
}

// ---------------- fused attention (round-11 core) + XCD-locality swizzle ----------------
// 1 wave/block, 2x16-query tiles, 64 keys/iter, 4 indep exp->LDS->PV chains.
// Swizzle: XCD assignment on MI355X is round-robin by linear block id (id % 8).
// Map id -> (xcd = id&7, j = id>>3): bh = xcd*16 + (j>>5), q0 = (j&31)*32.
// Each XCD owns 16 heads; 32 consecutive same-XCD blocks share one head's K/V
// (128 KB), so after first touch all K/V reads hit that XCD's 4 MB L2
// (per-XCD working set 2 MB vs previous 16 MB thrash).
#define PS 40   // P-tile LDS row stride (u16)
__global__ __launch_bounds__(64) void attn_kernel(
    const unsigned short* __restrict__ qr, const unsigned short* __restrict__ kr,
    const unsigned short* __restrict__ vt, unsigned short* __restrict__ ob)
{
    __shared__ __align__(16) unsigned short plds[4][16 * PS];  // [qt*2+kc], 5 KB
    int lane = threadIdx.x;
    int quad = lane >> 4, l16 = lane & 15;
    int id = blockIdx.x;
    int xcd = id & 7, j = id >> 3;
    int bh = xcd * 16 + (j >> 5);
    int q0 = (j & 31) * 32;
    int b = bh >> 3, h = bh & 7;
    const unsigned short* qbase = qr + ((size_t)bh * SS + q0) * DHH;
    const unsigned short* kbase = kr + (size_t)bh * SS * DHH;
    const unsigned short* vbase = vt + (size_t)bh * DHH * SS;
    bf16x8 qa[2];
    qa[0] = *(const bf16x8*)(qbase + (size_t)l16 * DHH + quad * 8);
    qa[1] = *(const bf16x8*)(qbase + (size_t)(16 + l16) * DHH + quad * 8);
    f32x4 o[2][2] = {};
    f32x2 lsum2[2][4] = {};
    for (int k0 = 0; k0 < SS; k0 += 64) {
        bf16x8 kb[2][2], vb[2][2];
        #pragma unroll
        for (int kc = 0; kc < 2; ++kc) {
            const unsigned short* kp = kbase + (size_t)(k0 + kc * 32) * DHH;
            kb[kc][0] = *(const bf16x8*)(kp + (size_t)l16 * DHH + quad * 8);        // even keys
            kb[kc][1] = *(const bf16x8*)(kp + (size_t)(16 + l16) * DHH + quad * 8); // odd keys
            vb[kc][0] = *(const bf16x8*)(vbase + (size_t)l16 * SS + k0 + kc * 32 + quad * 8);
            vb[kc][1] = *(const bf16x8*)(vbase + (size_t)(l16 + 16) * SS + k0 + kc * 32 + quad * 8);
        }
        #pragma unroll
        for (int qt = 0; qt < 2; ++qt)
            #pragma unroll
            for (int kc = 0; kc < 2; ++kc) {
                f32x4 z = {0.f, 0.f, 0.f, 0.f};
                f32x4 s0 = __builtin_amdgcn_mfma_f32_16x16x32_bf16(qa[qt], kb[kc][0], z, 0, 0, 0);
                f32x4 s1 = __builtin_amdgcn_mfma_f32_16x16x32_bf16(qa[qt], kb[kc][1], z, 0, 0, 0);
                #pragma unroll
                for (int r = 0; r < 4; ++r) {
                    float p0 = __builtin_amdgcn_exp2f(s0[r]);
                    float p1 = __builtin_amdgcn_exp2f(s1[r]);
                    lsum2[qt][r] += (f32x2){p0, p1};
                    *(unsigned int*)(&plds[qt * 2 + kc][(quad * 4 + r) * PS + 2 * l16]) =
                        packbf_perm(p0, p1);
                }
            }
        #pragma unroll
        for (int qt = 0; qt < 2; ++qt)
            #pragma unroll
            for (int kc = 0; kc < 2; ++kc) {
                bf16x8 pa = *(const bf16x8*)(&plds[qt * 2 + kc][l16 * PS + quad * 8]);
                o[qt][0] = __builtin_amdgcn_mfma_f32_16x16x32_bf16(pa, vb[kc][0], o[qt][0], 0, 0, 0);
                o[qt][1] = __builtin_amdgcn_mfma_f32_16x16x32_bf16(pa, vb[kc][1], o[qt][1], 0, 0, 0);
            }
    }
    #pragma unroll
    for (int qt = 0; qt < 2; ++qt)
        #pragma unroll
        for (int r = 0; r < 4; ++r) {
            float s = lsum2[qt][r][0] + lsum2[qt][r][1];
            s += __shfl_xor(s, 1);
            s += __shfl_xor(s, 2);
            s += __shfl_xor(s, 4);
            s += __shfl_xor(s, 8);
            float inv = 1.f / s;
            int qrow = q0 + qt * 16 + quad * 4 + r;
            size_t base = ((size_t)b * SS + qrow) * DD + h * DHH;
            ob[base + l16]      = f2bf(o[qt][0][r] * inv);
            ob[base + 16 + l16] = f2bf(o[qt][1][r] * inv);
        }
}

extern "C" void kernel_launch(void* const* d_in, const int* in_sizes, int n_in,
                              void* d_out, int out_size, void* d_ws, size_t ws_size,
                              hipStream_t stream)
{
    const float* x        = (const float*)d_in[0];
    const float* tok_w    = (const float*)d_in[1];
    const float* tok_b    = (const float*)d_in[2];
    const float* tnorm_g  = (const float*)d_in[3];
    const float* tnorm_b  = (const float*)d_in[4];
    const float* in_proj_w= (const float*)d_in[5];
    const float* in_proj_b= (const float*)d_in[6];
    const float* out_w    = (const float*)d_in[7];
    const float* out_b    = (const float*)d_in[8];
    const float* ln1_g    = (const float*)d_in[9];
    const float* ln1_b    = (const float*)d_in[10];
    const float* ln2_g    = (const float*)d_in[11];
    const float* ln2_b    = (const float*)d_in[12];
    const float* lin1_w   = (const float*)d_in[13];
    const float* lin1_b   = (const float*)d_in[14];
    const float* lin2_w   = (const float*)d_in[15];
    const float* lin2_b   = (const float*)d_in[16];
    const float* fnorm_g  = (const float*)d_in[17];
    const float* fnorm_b  = (const float*)d_in[18];

    char* ws = (char*)d_ws;
    unsigned short* wb        = (unsigned short*)ws;
    unsigned short* wb_tok    = wb;
    unsigned short* wb_inproj = wb + 131072;
    unsigned short* wb_out    = wb + 917504;
    unsigned short* wb_lin1   = wb + 1179648;
    unsigned short* wb_lin2   = wb + 2228224;
    unsigned short* qkvb = (unsigned short*)(ws + 6553600);
    unsigned short* xb   = qkvb;                                     // tokenize-only alias
    float*          h    = (float*)(ws + 31719424);
    unsigned short* y    = (unsigned short*)(ws + 48496640);
    unsigned short* qr   = (unsigned short*)(ws + 56885248);
    unsigned short* kr   = (unsigned short*)(ws + 65273856);
    unsigned short* vt   = (unsigned short*)(ws + 73662464);
    unsigned short* ob   = (unsigned short*)(ws + 82051072);
    unsigned short* a1   = (unsigned short*)(ws + 90439680);
    float*          t0   = (float*)(ws + 90439680);                  // aliases a1 (pre-layer only)

    convert_weights<<<dim3(12800), dim3(256), 0, stream>>>(tok_w, in_proj_w, out_w, lin1_w, lin2_w, wb);
    convert_x<<<dim3(8192), dim3(256), 0, stream>>>((const float4*)x, (ushort4*)xb, MROWS * TT / 4);

    // tokenize: t0 = x @ tok_w^T + tok_b ; h = LN(t0)
    gemm_n64<0><<<dim3(DD/64, MROWS/128), dim3(256), 0, stream>>>(
        xb, wb_tok, tok_b, nullptr, t0, MROWS, DD, TT);
    ln_rows<0><<<dim3(MROWS/4), dim3(256), 0, stream>>>(t0, tnorm_g, tnorm_b, h);

    for (int i = 0; i < LL; ++i) {
        ln_rows<1><<<dim3(MROWS/4), dim3(256), 0, stream>>>(h, ln1_g + i*DD, ln1_b + i*DD, y);
        gemm_lds<128,0><<<dim3((3*DD)/128, MROWS/128), dim3(256), 0, stream>>>(
            y, wb_inproj + (size_t)i*3*DD*DD, in_proj_b + i*3*DD, qkvb, MROWS, 3*DD, DD);
        rope_kernel<<<dim3(MROWS), dim3(256), 0, stream>>>(qkvb, qr, kr, vt);
        attn_kernel<<<dim3(4096), dim3(64), 0, stream>>>(qr, kr, vt, ob);
        gemm_n64<1><<<dim3(DD/64, MROWS/128), dim3(256), 0, stream>>>(
            ob, wb_out + (size_t)i*DD*DD, out_b + i*DD, h, h, MROWS, DD, DD);
        ln_rows<1><<<dim3(MROWS/4), dim3(256), 0, stream>>>(h, ln2_g + i*DD, ln2_b + i*DD, y);
        gemm_lds<256,1><<<dim3(FFN/256, MROWS/128), dim3(256), 0, stream>>>(
            y, wb_lin1 + (size_t)i*FFN*DD, lin1_b + i*FFN, a1, MROWS, FFN, DD);
        gemm_n64<1><<<dim3(DD/64, MROWS/128), dim3(256), 0, stream>>>(
            a1, wb_lin2 + (size_t)i*DD*FFN, lin2_b + i*DD, h, h, MROWS, DD, FFN);
    }
    ln_rows<0><<<dim3(MROWS/4), dim3(256), 0, stream>>>(h, fnorm_g, fnorm_b, (float*)d_out);
}